// Round 1
// 227.397 us; speedup vs baseline: 1.0641x; 1.0641x over previous
//
#include <hip/hip_runtime.h>
#include <hip/hip_bf16.h>
#include <math.h>

// Problem constants
#define B_   2
#define S_   2048
#define DM_  1024
#define H_   16
#define HD_  64
#define MEM_ 1000
#define KTOT 10
#define NROW (B_ * S_)          // 4096
#define NEG9 (-1e9f)
#define LDK  72                 // bf16 row stride in attention LDS tiles
#define NITEMS 1024             // attention work items: 32 qt x 16 h x 2 b

typedef __attribute__((ext_vector_type(8))) short short8;
typedef __attribute__((ext_vector_type(4))) float f32x4;

// async global->LDS, 16B per lane, dest = wave-uniform base + lane*16
__device__ __forceinline__ void gll16(const __hip_bfloat16* g, __hip_bfloat16* l) {
    __builtin_amdgcn_global_load_lds(
        (const __attribute__((address_space(1))) void*)g,
        (__attribute__((address_space(3))) void*)l, 16, 0, 0);
}

// ---------------------------------------------------------------------------
// prep: fused prologue (independent parts, branch on block range).
//   blocks [0,2048):    inputs fp32 -> bf16 Ax
//   blocks [2048,3072): weights fp32 -> transposed bf16 Wt[g*1024+n][k]
//   blocks [3072,3104): last-row K in fp32 (retrieval stays exact)
//   block 0 thread 0:   zero the attention work-steal counter
// ---------------------------------------------------------------------------
__global__ __launch_bounds__(256) void prep(const float* __restrict__ inputs,
                                            const float* __restrict__ Wq,
                                            const float* __restrict__ Wk,
                                            const float* __restrict__ Wv,
                                            const float* __restrict__ Wo,
                                            __hip_bfloat16* __restrict__ Ax,
                                            __hip_bfloat16* __restrict__ Wt,
                                            float* __restrict__ lk,
                                            int* __restrict__ ctr) {
    const int bx = blockIdx.x, tid = threadIdx.x;
    if (bx == 0 && tid == 0) *ctr = 0;

    if (bx < 2048) {
        const size_t i = ((size_t)bx * 256 + tid) * 8;
        float4 a = *(const float4*)&inputs[i];
        float4 b = *(const float4*)&inputs[i + 4];
        alignas(16) __hip_bfloat16 t[8];
        t[0] = __float2bfloat16(a.x); t[1] = __float2bfloat16(a.y);
        t[2] = __float2bfloat16(a.z); t[3] = __float2bfloat16(a.w);
        t[4] = __float2bfloat16(b.x); t[5] = __float2bfloat16(b.y);
        t[6] = __float2bfloat16(b.z); t[7] = __float2bfloat16(b.w);
        *(short8*)&Ax[i] = *(short8*)t;
        return;
    }
    if (bx < 3072) {
        const int idx = bx - 2048;
        const int g = idx >> 8, rem = idx & 255;
        const float* W = (g == 0) ? Wq : (g == 1) ? Wk : (g == 2) ? Wv : Wo;
        const int n0 = (rem & 15) * 64, k0 = (rem >> 4) * 64;
        __shared__ float T[64][65];
        {
            const int r = tid >> 4, c4 = (tid & 15) * 4;
#pragma unroll
            for (int p = 0; p < 4; ++p) {
                float4 v = *(const float4*)&W[(size_t)(k0 + r + p * 16) * 1024 + n0 + c4];
                T[r + p * 16][c4 + 0] = v.x; T[r + p * 16][c4 + 1] = v.y;
                T[r + p * 16][c4 + 2] = v.z; T[r + p * 16][c4 + 3] = v.w;
            }
        }
        __syncthreads();
        {
            const int n = tid >> 3, off = (tid & 7) * 8;
#pragma unroll
            for (int p = 0; p < 2; ++p) {
                const int nn = n + p * 32;
                alignas(16) __hip_bfloat16 t[8];
#pragma unroll
                for (int j = 0; j < 8; ++j) t[j] = __float2bfloat16(T[off + j][nn]);
                *(short8*)&Wt[((size_t)(g * 1024 + n0 + nn)) * 1024 + k0 + off] = *(short8*)t;
            }
        }
        return;
    }
    {   // lastk: lk[b,:] = inputs[b, S-1, :] @ Wk (fp32)
        const int idx = bx - 3072;
        const int xblk = idx & 15, b = idx >> 4;
        const int cl = tid & 63;
        const int col = xblk * 64 + cl;
        const int kq = tid >> 6;
        __shared__ float xr[1024];
        __shared__ float part[4][64];
        for (int i = tid; i < 1024; i += 256)
            xr[i] = inputs[((size_t)(b * S_ + S_ - 1)) * 1024 + i];
        __syncthreads();
        float acc = 0.f;
#pragma unroll 4
        for (int k = kq * 256; k < kq * 256 + 256; ++k)
            acc += xr[k] * Wk[(size_t)k * 1024 + col];
        part[kq][cl] = acc;
        __syncthreads();
        if (tid < 64)
            lk[b * 1024 + xblk * 64 + tid] =
                part[0][tid] + part[1][tid] + part[2][tid] + part[3][tid];
    }
}

// ---------------------------------------------------------------------------
// bf16 MFMA GEMM, m97 structure: BK=32, unpadded [128][32] LDS tiles staged
// with global_load_lds dwordx4. 128x128 tile, 4 waves, 16 MFMA per k-iter.
// ---------------------------------------------------------------------------
__device__ __forceinline__ void store_out(__hip_bfloat16* p, float x) { *p = __float2bfloat16(x); }
__device__ __forceinline__ void store_out(float* p, float x) { *p = x; }

template <typename OutT>
__global__ __launch_bounds__(256) void gemm_mfma(const __hip_bfloat16* __restrict__ A,
                                                 const __hip_bfloat16* __restrict__ Bt,
                                                 OutT* __restrict__ C, int ldc) {
    __shared__ __hip_bfloat16 As[128 * 32];
    __shared__ __hip_bfloat16 Bs[128 * 32];
    const int tid = threadIdx.x;
    const int wave = tid >> 6, lane = tid & 63;
    const int quad = lane >> 4, lm = lane & 15;
    const int wr = wave >> 1, wc = wave & 1;
    const int m0 = blockIdx.y * 128, n0 = blockIdx.x * 128;

    const int r0 = tid >> 2, c0 = (tid & 3) * 8;
    const __hip_bfloat16* ga0 = &A[(size_t)(m0 + r0) * 1024 + c0];
    const __hip_bfloat16* ga1 = &A[(size_t)(m0 + 64 + r0) * 1024 + c0];
    const __hip_bfloat16* gb0 = &Bt[(size_t)(n0 + r0) * 1024 + c0];
    const __hip_bfloat16* gb1 = &Bt[(size_t)(n0 + 64 + r0) * 1024 + c0];
    __hip_bfloat16* la0 = &As[(wave * 64) * 8];
    __hip_bfloat16* la1 = &As[(256 + wave * 64) * 8];
    __hip_bfloat16* lb0 = &Bs[(wave * 64) * 8];
    __hip_bfloat16* lb1 = &Bs[(256 + wave * 64) * 8];

    f32x4 acc[4][4];
#pragma unroll
    for (int i = 0; i < 4; ++i)
#pragma unroll
        for (int j = 0; j < 4; ++j) acc[i][j] = (f32x4){0.f, 0.f, 0.f, 0.f};

    for (int k0 = 0; k0 < 1024; k0 += 32) {
        __syncthreads();
        gll16(ga0 + k0, la0);
        gll16(ga1 + k0, la1);
        gll16(gb0 + k0, lb0);
        gll16(gb1 + k0, lb1);
        __syncthreads();
        short8 af[4], bf4[4];
#pragma unroll
        for (int mt = 0; mt < 4; ++mt)
            af[mt] = *(const short8*)&As[(wr * 64 + mt * 16 + lm) * 32 + quad * 8];
#pragma unroll
        for (int nt = 0; nt < 4; ++nt)
            bf4[nt] = *(const short8*)&Bs[(wc * 64 + nt * 16 + lm) * 32 + quad * 8];
#pragma unroll
        for (int mt = 0; mt < 4; ++mt)
#pragma unroll
            for (int nt = 0; nt < 4; ++nt)
                acc[mt][nt] = __builtin_amdgcn_mfma_f32_16x16x32_bf16(
                    af[mt], bf4[nt], acc[mt][nt], 0, 0, 0);
    }
#pragma unroll
    for (int mt = 0; mt < 4; ++mt)
#pragma unroll
        for (int nt = 0; nt < 4; ++nt) {
            const int col = n0 + wc * 64 + nt * 16 + lm;
#pragma unroll
            for (int i = 0; i < 4; ++i) {
                const int row = m0 + wr * 64 + mt * 16 + quad * 4 + i;
                store_out(&C[(size_t)row * ldc + col], acc[mt][nt][i]);
            }
        }
}

// ---------------------------------------------------------------------------
// R9: 64x128-tile variant for the out-projection GEMM (M=4096,N=1024,K=1024).
// The 128x128 grid there was 8x32 = 256 blocks = 1 block/CU = 1 wave/SIMD —
// latency-exposed. 64x128 doubles the grid to 512 blocks = 2 blocks/CU.
// Wave tile 32x64: acc[2][4], 3 gll16 per k-step (As is one 4KB stage).
// ---------------------------------------------------------------------------
template <typename OutT>
__global__ __launch_bounds__(256) void gemm_mfma64(const __hip_bfloat16* __restrict__ A,
                                                   const __hip_bfloat16* __restrict__ Bt,
                                                   OutT* __restrict__ C, int ldc) {
    __shared__ __hip_bfloat16 As[64 * 32];
    __shared__ __hip_bfloat16 Bs[128 * 32];
    const int tid = threadIdx.x;
    const int wave = tid >> 6, lane = tid & 63;
    const int quad = lane >> 4, lm = lane & 15;
    const int wr = wave >> 1, wc = wave & 1;    // wave tile: 32 rows x 64 cols
    const int m0 = blockIdx.y * 64, n0 = blockIdx.x * 128;

    const int r0 = tid >> 2, c0 = (tid & 3) * 8;
    const __hip_bfloat16* ga  = &A[(size_t)(m0 + r0) * 1024 + c0];
    const __hip_bfloat16* gb0 = &Bt[(size_t)(n0 + r0) * 1024 + c0];
    const __hip_bfloat16* gb1 = &Bt[(size_t)(n0 + 64 + r0) * 1024 + c0];
    __hip_bfloat16* la  = &As[(wave * 64) * 8];
    __hip_bfloat16* lb0 = &Bs[(wave * 64) * 8];
    __hip_bfloat16* lb1 = &Bs[(256 + wave * 64) * 8];

    f32x4 acc[2][4];
#pragma unroll
    for (int i = 0; i < 2; ++i)
#pragma unroll
        for (int j = 0; j < 4; ++j) acc[i][j] = (f32x4){0.f, 0.f, 0.f, 0.f};

    for (int k0 = 0; k0 < 1024; k0 += 32) {
        __syncthreads();
        gll16(ga + k0, la);
        gll16(gb0 + k0, lb0);
        gll16(gb1 + k0, lb1);
        __syncthreads();
        short8 af[2], bf4[4];
#pragma unroll
        for (int mt = 0; mt < 2; ++mt)
            af[mt] = *(const short8*)&As[(wr * 32 + mt * 16 + lm) * 32 + quad * 8];
#pragma unroll
        for (int nt = 0; nt < 4; ++nt)
            bf4[nt] = *(const short8*)&Bs[(wc * 64 + nt * 16 + lm) * 32 + quad * 8];
#pragma unroll
        for (int mt = 0; mt < 2; ++mt)
#pragma unroll
            for (int nt = 0; nt < 4; ++nt)
                acc[mt][nt] = __builtin_amdgcn_mfma_f32_16x16x32_bf16(
                    af[mt], bf4[nt], acc[mt][nt], 0, 0, 0);
    }
#pragma unroll
    for (int mt = 0; mt < 2; ++mt)
#pragma unroll
        for (int nt = 0; nt < 4; ++nt) {
            const int col = n0 + wc * 64 + nt * 16 + lm;
#pragma unroll
            for (int i = 0; i < 4; ++i) {
                const int row = m0 + wr * 32 + mt * 16 + quad * 4 + i;
                store_out(&C[(size_t)row * ldc + col], acc[mt][nt][i]);
            }
        }
}

// ---------------------------------------------------------------------------
// sims[b][m] = (qvec . e_m) / (|e_m| + 1e-8)  (1/|q| > 0 cannot change order).
// ---------------------------------------------------------------------------
__global__ __launch_bounds__(256) void sims_kernel(const float* __restrict__ lk,
                                                   const float* __restrict__ events,
                                                   float* __restrict__ sims) {
    const int b = blockIdx.y;
    const int tid = threadIdx.x;
    const int wave = tid >> 6, lane = tid & 63;
    __shared__ float qv[1024];
    for (int i = tid; i < 1024; i += 256)
        qv[i] = lk[b * 1024 + i];
    __syncthreads();

    const int m = blockIdx.x * 4 + wave;
    if (m >= MEM_) return;
    const float* ev = &events[(size_t)m * 1024];
    float dot = 0.f, nrm = 0.f;
    for (int d = lane; d < 1024; d += 64) {
        float e = ev[d];
        dot += qv[d] * e;
        nrm += e * e;
    }
    for (int off = 32; off; off >>= 1) {
        dot += __shfl_down(dot, off);
        nrm += __shfl_down(nrm, off);
    }
    if (lane == 0) sims[b * 1024 + m] = dot / (sqrtf(nrm) + 1e-8f);
}

// ---------------------------------------------------------------------------
// Top-10, single wave per batch: 16 values/lane in registers, shuffle-only
// argmax x10, smaller-index tie-break. No barriers, no LDS.
// ---------------------------------------------------------------------------
__global__ __launch_bounds__(64) void topk10_kernel(const float* __restrict__ sims,
                                                    int* __restrict__ topk) {
    const int b = blockIdx.x;
    const int lane = threadIdx.x;
    const int base = lane * 16;
    float v[16];
#pragma unroll
    for (int j = 0; j < 16; ++j) {
        const int m = base + j;
        v[j] = (m < MEM_) ? sims[b * 1024 + m] : -INFINITY;
    }
    for (int it = 0; it < KTOT; ++it) {
        float best = -INFINITY; int bi = 0x7fffffff;
#pragma unroll
        for (int j = 0; j < 16; ++j)
            if (v[j] > best) { best = v[j]; bi = base + j; }   // strict > keeps smallest idx
        for (int off = 32; off; off >>= 1) {
            const float ob = __shfl_xor(best, off);
            const int   oi = __shfl_xor(bi, off);
            if (ob > best || (ob == best && oi < bi)) { best = ob; bi = oi; }
        }
        if (lane == 0) topk[b * KTOT + it] = bi;
#pragma unroll
        for (int j = 0; j < 16; ++j)
            if (base + j == bi) v[j] = -INFINITY;
    }
}

// ---------------------------------------------------------------------------
// Flash attention, bf16 MFMA, persistent blocks + work stealing (768 blocks,
// 1024 items in LPT order).
// R9 changes (latency attack — the kernel was 9% Mfma / 24% VALU / 20% occ,
// i.e. serialization-bound, makespan = 33-tile chains at ~2 us/tile):
//  * K/V/colb DOUBLE-BUFFERED in LDS -> ONE barrier per KV tile instead of
//    two. Per-tile schedule: [qk;softmax;pv on buf A] -> [stage kt+1 -> buf B]
//    -> [prefetch kt+2 -> regs] -> barrier. The global-load latency window is
//    now a full tile of compute, and the stage's vmcnt wait sits after all
//    MFMA/VALU work instead of in front of it. Tile kt lives in buf (kt+1)&1;
//    memory tile in buf 0. LDS 30.7 -> 51.3 KB (still 3 blocks/CU, grid 768
//    = 3/CU, so no occupancy loss).
//  * per-ITEM Vt zeroing removed: masked columns have Ps = exp(-1e9-m) = 0.0
//    exactly, and 0 * stale-finite-bf16 = 0. Only initial LDS garbage could
//    be NaN, so both Vt buffers are zeroed ONCE at kernel start (also drops
//    one barrier + 9 KB of LDS writes per item).
// Kept from R8: ones-column l-accumulator (Vt rows 64..79, row 64 = 1.0),
// Q fragments in registers, frozen-max + exact-underflow tile skip.
// ---------------------------------------------------------------------------
__global__ __launch_bounds__(256) void attn_mfma(
        const __hip_bfloat16* __restrict__ qkv,
        const float* __restrict__ events,
        const int* __restrict__ topk,
        const float* __restrict__ amask,
        __hip_bfloat16* __restrict__ out,
        int* __restrict__ ctr) {
    const int tid = threadIdx.x;
    const int wave = tid >> 6, lane = tid & 63;
    const int quad = lane >> 4, lm = lane & 15;

    const __hip_bfloat16* qf = qkv;
    const __hip_bfloat16* kf = qkv + 1024;
    const __hip_bfloat16* vf = qkv + 2048;

    __shared__ __hip_bfloat16 Ks[2][64 * LDK];
    __shared__ __hip_bfloat16 Vt[2][80 * LDK];   // [d][kcol]; rows 64..79 static (64=ones)
    __shared__ __hip_bfloat16 Ps[64 * LDK];
    __shared__ float colb[2][64];
    __shared__ float redb[4];
    __shared__ int sItem;

    const int va = tid & 31, vdc = tid >> 5;
    const int vtok0 = va * 2, vd0 = vdc * 8;

    // one-time init: finite fill of dynamic Vt rows (stale-x-0 = 0 needs
    // finite, not zero; first item must not see NaN bit patterns), and the
    // static ones/zero rows of both buffers.
    for (int i = tid * 8; i < 64 * LDK; i += 256 * 8) {
        *(int4*)&Vt[0][i] = make_int4(0, 0, 0, 0);
        *(int4*)&Vt[1][i] = make_int4(0, 0, 0, 0);
    }
    for (int i = tid; i < 16 * LDK; i += 256) {
        const int r = i / LDK;
        const __hip_bfloat16 v = __float2bfloat16(r == 0 ? 1.0f : 0.0f);
        Vt[0][64 * LDK + i] = v;
        Vt[1][64 * LDK + i] = v;
    }

    for (;;) {
        __syncthreads();    // prev item's LDS readers done; also covers Vt init
        if (tid == 0) sItem = atomicAdd(ctr, 1);
        __syncthreads();
        const int n = sItem;
        if (n >= NITEMS) break;

        const int qt = 31 - (n >> 5);
        const int q0 = qt * 64;
        const int inner = n & 31;
        const int h = 15 - ((inner >> 1) & 15);
        const int b = inner & 1;
        const float slope = exp2f(-0.5f * (float)(h + 1));

        short8 pk[2], pv0, pv1;
        float pam = 1.f;
        auto prefetchKV = [&](int kt) {
            const __hip_bfloat16* ks = &kf[((size_t)(b * S_ + kt * 64)) * 3072 + h * 64];
#pragma unroll
            for (int u = 0; u < 2; ++u) {
                int c = tid * 2 + u, row = c >> 3, off = (c & 7) * 8;
                pk[u] = *(const short8*)&ks[(size_t)row * 3072 + off];
            }
            const __hip_bfloat16* v0 =
                &vf[((size_t)(b * S_ + kt * 64 + vtok0)) * 3072 + h * 64 + vd0];
            pv0 = *(const short8*)v0;
            pv1 = *(const short8*)(v0 + 3072);
            if (tid < 64) pam = amask[b * S_ + kt * 64 + tid];
        };
        auto stageKV = [&](int kt, int pb) {
#pragma unroll
            for (int u = 0; u < 2; ++u) {
                int c = tid * 2 + u, row = c >> 3, off = (c & 7) * 8;
                *(short8*)&Ks[pb][row * LDK + off] = pk[u];
            }
#pragma unroll
            for (int j = 0; j < 8; ++j) {
                short2 pr; pr.x = pv0[j]; pr.y = pv1[j];
                *(short2*)&Vt[pb][(vd0 + j) * LDK + vtok0] = pr;
            }
            if (tid < 64)
                colb[pb][tid] = fmaf(-slope, (float)(kt * 64 + tid), (1.f - pam) * NEG9);
        };

        prefetchKV(0);      // earliest possible issue; consumed by stageKV(0,1)

        // ---- Q fragments straight into registers ----
        short8 qa[2];
        {
            const __hip_bfloat16* qsrc =
                &qf[((size_t)(b * S_ + q0 + wave * 16 + lm)) * 3072 + h * 64 + quad * 8];
            qa[0] = *(const short8*)qsrc;
            qa[1] = *(const short8*)(qsrc + 32);
        }
        // memory tile -> buf 0 (K rows 0..9; Vt cols 0..9; stale rest is
        // masked: Ks via cc>=KTOT -> NEG9, Vt via Ps == 0.0 exactly)
        if (tid < 80) {
            const int tok = tid >> 3, d0 = (tid & 7) * 8;
            const int ev = topk[b * KTOT + tok];
            const float* es = &events[(size_t)ev * 1024 + h * 64 + d0];
#pragma unroll
            for (int j = 0; j < 8; ++j) {
                __hip_bfloat16 x = __float2bfloat16(es[j]);
                Ks[0][tok * LDK + d0 + j] = x;
                Vt[0][(d0 + j) * LDK + tok] = x;
            }
        }
        __syncthreads();

        float m_[4], mshift[4];
        f32x4 Oa[5];        // Oa[4] = softmax denominator column
#pragma unroll
        for (int i = 0; i < 4; ++i) {
            m_[i] = -INFINITY;
            mshift[i] = -slope * (float)(q0 + wave * 16 + quad * 4 + i);
        }
#pragma unroll
        for (int nt = 0; nt < 5; ++nt) Oa[nt] = (f32x4){0.f, 0.f, 0.f, 0.f};

        auto qk = [&](f32x4* sa, const __hip_bfloat16* Kp) {
#pragma unroll
            for (int nt = 0; nt < 4; ++nt) sa[nt] = (f32x4){0.f, 0.f, 0.f, 0.f};
#pragma unroll
            for (int ks2 = 0; ks2 < 2; ++ks2) {
#pragma unroll
                for (int nt = 0; nt < 4; ++nt) {
                    short8 bk = *(const short8*)&Kp[(nt * 16 + lm) * LDK + ks2 * 32 + quad * 8];
                    sa[nt] = __builtin_amdgcn_mfma_f32_16x16x32_bf16(qa[ks2], bk, sa[nt], 0, 0, 0);
                }
            }
        };
        auto pv = [&](const __hip_bfloat16* Vp) {
#pragma unroll
            for (int ks2 = 0; ks2 < 2; ++ks2) {
                short8 ap = *(const short8*)&Ps[(wave * 16 + lm) * LDK + ks2 * 32 + quad * 8];
#pragma unroll
                for (int nt = 0; nt < 5; ++nt) {   // nt=4: ones column -> l
                    short8 bv = *(const short8*)&Vp[(nt * 16 + lm) * LDK + ks2 * 32 + quad * 8];
                    Oa[nt] = __builtin_amdgcn_mfma_f32_16x16x32_bf16(ap, bv, Oa[nt], 0, 0, 0);
                }
            }
        };

        auto softmax_online = [&](const f32x4* sa, int kt, bool diag, const float* cbp) {
            float cb[4];
            if (kt >= 0) {
#pragma unroll
                for (int nt = 0; nt < 4; ++nt) cb[nt] = cbp[nt * 16 + lm];
            }
#pragma unroll
            for (int i = 0; i < 4; ++i) {
                const int lr = wave * 16 + quad * 4 + i;
                const int rg = q0 + lr;
                float s[4];
#pragma unroll
                for (int nt = 0; nt < 4; ++nt) {
                    const int cc = nt * 16 + lm;
                    if (kt < 0) {
                        s[nt] = (cc < KTOT) ? fmaf(sa[nt][i], 0.125f, mshift[i]) : NEG9;
                    } else {
                        float v = fmaf(sa[nt][i], 0.125f, cb[nt]);
                        s[nt] = (diag && kt * 64 + cc > rg) ? NEG9 : v;
                    }
                }
                float rmax = fmaxf(fmaxf(s[0], s[1]), fmaxf(s[2], s[3]));
#pragma unroll
                for (int off = 1; off < 16; off <<= 1)
                    rmax = fmaxf(rmax, __shfl_xor(rmax, off, 16));
                const float newm = fmaxf(m_[i], rmax);
                const float al = __expf(m_[i] - newm);
                m_[i] = newm;
#pragma unroll
                for (int nt = 0; nt < 4; ++nt)
                    Ps[lr * LDK + nt * 16 + lm] = __float2bfloat16(__expf(s[nt] - newm));
#pragma unroll
                for (int nt = 0; nt < 5; ++nt)     // includes l-column
                    Oa[nt][i] *= al;
            }
        };

        auto softmax_fast = [&](const f32x4* sa, int cbase, bool diag, const float* cbp) {
            float cb[4];
#pragma unroll
            for (int nt = 0; nt < 4; ++nt) cb[nt] = cbp[nt * 16 + lm];
#pragma unroll
            for (int i = 0; i < 4; ++i) {
                const int lr = wave * 16 + quad * 4 + i;
                const float cm = m_[i];
                float p[4];
#pragma unroll
                for (int nt = 0; nt < 4; ++nt)
                    p[nt] = __expf(fmaf(sa[nt][i], 0.125f, cb[nt]) - cm);
                if (diag) {
                    const int rg = q0 + lr;
#pragma unroll
                    for (int nt = 0; nt < 4; ++nt)
                        if (cbase + nt * 16 + lm > rg) p[nt] = 0.f;
                }
#pragma unroll
                for (int nt = 0; nt < 4; ++nt)
                    Ps[lr * LDK + nt * 16 + lm] = __float2bfloat16(p[nt]);
            }
        };

        // ---- memory tile (online) on buf0; stage kt0 -> buf1 behind it ----
        {
            f32x4 sa[4];
            qk(sa, Ks[0]);
            softmax_online(sa, -1, false, nullptr);
            pv(Vt[0]);
        }
        stageKV(0, 1);
        if (qt >= 1) prefetchKV(1);
        __syncthreads();

        // ---- kt = 0 (online) on buf1; stage kt1 -> buf0 behind it ----
        {
            f32x4 sa[4];
            qk(sa, Ks[1]);
            softmax_online(sa, 0, qt == 0, colb[1]);
            pv(Vt[1]);
        }
        // freeze max: wave-min -> redb (read after the same barrier that
        // publishes the staged tile 1)
        {
            float mloc = fminf(fminf(m_[0], m_[1]), fminf(m_[2], m_[3]));
#pragma unroll
            for (int off = 1; off < 64; off <<= 1)
                mloc = fminf(mloc, __shfl_xor(mloc, off, 64));
            if (lane == 0) redb[wave] = mloc;
        }
        if (qt >= 1) stageKV(1, 0);
        if (qt >= 2) prefetchKV(2);
        __syncthreads();

        int ktend = 0;
        if (qt >= 1) {
            const float mmin = fminf(fminf(redb[0], redb[1]), fminf(redb[2], redb[3]));
            ktend = min(qt, (int)((118.f - mmin) / (64.f * slope)));
        }
        // steady state: ONE barrier per tile; tile kt lives in buf (kt+1)&1
        for (int kt = 1; kt <= ktend; ++kt) {
            const int pb = (kt + 1) & 1;
            f32x4 sa[4];
            qk(sa, Ks[pb]);
            softmax_fast(sa, kt * 64, kt == qt, colb[pb]);
            pv(Vt[pb]);
            if (kt < ktend) stageKV(kt + 1, kt & 1);
            if (kt + 1 < ktend) prefetchKV(kt + 2);
            __syncthreads();
        }

        // ---- epilogue: l lives in Oa[4] col 0 (lanes lm==0); broadcast ----
#pragma unroll
        for (int i = 0; i < 4; ++i) {
            const int lr = wave * 16 + quad * 4 + i;
            const float l = __shfl(Oa[4][i], (lane & 48));
            const float inv = 1.f / l;
            __hip_bfloat16* dst = &out[((size_t)(b * S_ + q0 + lr)) * 1024 + h * 64 + lm];
#pragma unroll
            for (int nt = 0; nt < 4; ++nt)
                dst[nt * 16] = __float2bfloat16(Oa[nt][i] * inv);
        }
    }
}

// ---------------------------------------------------------------------------
extern "C" void kernel_launch(void* const* d_in, const int* in_sizes, int n_in,
                              void* d_out, int out_size, void* d_ws, size_t ws_size,
                              hipStream_t stream) {
    const float* inputs = (const float*)d_in[0];
    const float* amask  = (const float*)d_in[1];
    const float* Wq     = (const float*)d_in[2];
    const float* Wk     = (const float*)d_in[3];
    const float* Wv     = (const float*)d_in[4];
    const float* Wo     = (const float*)d_in[5];
    const float* events = (const float*)d_in[6];
    float* out = (float*)d_out;

    // ws: Ax 8MB | Wt 8MB | qkv 24MB | ao 8MB | lk | sims | topk | ctr
    __hip_bfloat16* Ax  = (__hip_bfloat16*)d_ws;
    __hip_bfloat16* Wt  = Ax + (size_t)NROW * 1024;
    __hip_bfloat16* qkv = Wt + (size_t)4096 * 1024;
    __hip_bfloat16* ao  = qkv + (size_t)NROW * 3072;
    float* lk   = (float*)(ao + (size_t)NROW * 1024);
    float* sims = lk + 2 * 1024;
    int* topk   = (int*)(sims + 2 * 1024);
    int* ctr    = topk + B_ * KTOT;

    dim3 blk(256);
    prep<<<3104, blk, 0, stream>>>(inputs, Wq, Wk, Wv, Wo, Ax, Wt, lk, ctr);
    sims_kernel<<<dim3(250, B_), blk, 0, stream>>>(lk, events, sims);
    topk10_kernel<<<B_, 64, 0, stream>>>(sims, topk);
    gemm_mfma<__hip_bfloat16><<<dim3(24, 32), blk, 0, stream>>>(Ax, Wt, qkv, 3072);
    attn_mfma<<<768, blk, 0, stream>>>(qkv, events, topk, amask, ao, ctr);
    gemm_mfma64<float><<<dim3(8, 64), blk, 0, stream>>>(
        ao, Wt + (size_t)3072 * 1024, out, 1024);
}